// Round 8
// baseline (369.905 us; speedup 1.0000x reference)
//
#include <hip/hip_runtime.h>

typedef unsigned short u16;
typedef unsigned int u32;
typedef __attribute__((ext_vector_type(4))) float f32x4;
typedef __attribute__((ext_vector_type(8))) short bf16x8;
typedef __attribute__((ext_vector_type(4))) unsigned short u16x4;

#define MFMA(a, b, c) __builtin_amdgcn_mfma_f32_16x16x32_bf16((a), (b), (c), 0, 0, 0)

static constexpr int M_TOK = 8192;  // B*S

__device__ __forceinline__ u16 f2bf(float f) {
  u32 u = __float_as_uint(f);
  return (u16)((u + 0x7FFFu + ((u >> 16) & 1u)) >> 16);  // RNE
}
__device__ __forceinline__ float bf2f(u16 b) {
  u32 u = ((u32)b) << 16;
  return __uint_as_float(u);
}
__device__ __forceinline__ void gload16(const u16* g, u16* l) {
  __builtin_amdgcn_global_load_lds(
      (const __attribute__((address_space(1))) u32*)(const void*)g,
      (__attribute__((address_space(3))) u32*)(void*)l, 16, 0, 0);
}

#define PH_BAR()                                     \
  do {                                               \
    __builtin_amdgcn_sched_barrier(0);               \
    __builtin_amdgcn_s_barrier();                    \
    asm volatile("s_waitcnt lgkmcnt(0)" ::: "memory"); \
    __builtin_amdgcn_sched_barrier(0);               \
  } while (0)
#define PH_END()                       \
  do {                                 \
    __builtin_amdgcn_sched_barrier(0); \
    __builtin_amdgcn_s_barrier();      \
  } while (0)

// ---- elementwise fp32 -> bf16 cast ----
__global__ void cast_x_kernel(const float* __restrict__ in, u16* __restrict__ out, int total4) {
  for (int i = blockIdx.x * blockDim.x + threadIdx.x; i < total4; i += gridDim.x * blockDim.x) {
    float4 v = ((const float4*)in)[i];
    u16x4 o;
    o[0] = f2bf(v.x); o[1] = f2bf(v.y); o[2] = f2bf(v.z); o[3] = f2bf(v.w);
    ((u16x4*)out)[i] = o;
  }
}

// ---- transpose + cast: in [z][P][Q] fp32 -> out [z][Q][P] bf16 ----
__global__ void tcast_kernel(const float* __restrict__ in, u16* __restrict__ out, int P, int Q) {
  __shared__ float tile[32][33];
  const int z = blockIdx.z;
  const int q0 = blockIdx.x * 32, p0 = blockIdx.y * 32;
  const float* src = in + (size_t)z * P * Q;
  u16* dst = out + (size_t)z * P * Q;
  const int tx = threadIdx.x & 31, ty = threadIdx.x >> 5;
#pragma unroll
  for (int k = 0; k < 4; ++k)
    tile[ty + k * 8][tx] = src[(size_t)(p0 + ty + k * 8) * Q + q0 + tx];
  __syncthreads();
#pragma unroll
  for (int k = 0; k < 4; ++k)
    dst[(size_t)(q0 + ty + k * 8) * P + p0 + tx] = f2bf(tile[tx][ty + k * 8]);
}

// ---- h[m,r] = sum_n wf[m,n] * T[m, n*256+r] -> bf16 ----
__global__ void combine_h(const u16* __restrict__ T, const float* __restrict__ Wf,
                          u16* __restrict__ h) {
  const int m = blockIdx.x * 4 + (threadIdx.x >> 6);
  const int lane = threadIdx.x & 63;
  const u16* rowp = T + (size_t)m * 4096;
  float h0 = 0.f, h1 = 0.f, h2 = 0.f, h3 = 0.f;
#pragma unroll
  for (int n = 0; n < 16; ++n) {
    u16x4 v = *(const u16x4*)&rowp[n * 256 + lane * 4];
    const float wf = Wf[(size_t)m * 16 + n];
    h0 += wf * bf2f(v[0]); h1 += wf * bf2f(v[1]);
    h2 += wf * bf2f(v[2]); h3 += wf * bf2f(v[3]);
  }
  u16x4 o;
  o[0] = f2bf(h0); o[1] = f2bf(h1); o[2] = f2bf(h2); o[3] = f2bf(h3);
  *(u16x4*)&h[(size_t)m * 256 + lane * 4] = o;
}

// ================= GEMM1: 256x256, merged 4-phase, ks-outer MFMA =================
template <int NT>
__global__ __launch_bounds__(512, 2) void gemm256(
    const u16* __restrict__ A, const u16* __restrict__ Bm, void* __restrict__ OutV,
    const int N, const int K) {
  constexpr int NITER = NT / 2;
  __shared__ u16 lds[65536];  // A: [0,32K) u16, B: [32K,64K) u16 (128 KB)

  const int tid = threadIdx.x;
  const int lane = tid & 63;
  const int wid = tid >> 6;
  const int wr = wid >> 2, wc = wid & 3;

  // L2-aware chunked XCD swizzle (grid 16x32 = 512)
  const int L = blockIdx.y * gridDim.x + blockIdx.x;
  const int ordered = (L & 7) * 64 + (L >> 3);
  const int cid = ordered >> 5, win = ordered & 31;
  const int bx = (cid & 3) * 4 + (win & 3);
  const int by = (cid >> 2) * 8 + (win >> 2);
  const int m0 = by * 256, bn0 = bx * 256;

  const int arow = lane & 15;
  const int acol = (lane >> 4) * 16;
  const int sw = (arow & 7) << 4;
  const int lo0 = arow * 128 + (acol ^ sw);
  const int lo1 = arow * 128 + ((64 + acol) ^ sw);

  const u16* Abase = A + (size_t)m0 * K;
  const u16* Bbase = Bm + (size_t)bn0 * K;

  f32x4 acc[8][4];
#pragma unroll
  for (int i = 0; i < 8; ++i)
#pragma unroll
    for (int j = 0; j < 4; ++j) acc[i][j] = (f32x4){0.f, 0.f, 0.f, 0.f};

  auto STAGE = [&](int b, int isB, int hf, int kt) {
    const u16* G = isB ? Bbase : Abase;
    u16* Lp = &lds[isB * 32768 + (b * 2 + hf) * 8192];
#pragma unroll
    for (int j = 0; j < 2; ++j) {
      const int q = j * 8192 + tid * 16;
      const int grow = q >> 7;
      const int gcol = ((q & 127) ^ (((q >> 7) & 7) << 4)) >> 1;
      gload16(G + (size_t)(hf * 128 + grow) * K + kt * 64 + gcol,
              Lp + ((j * 8192 + wid * 1024) >> 1));
    }
  };
  auto LOAD_AV = [&](bf16x8 (&v)[4][2], int b, int mh) {
    const char* p = (const char*)lds + b * 32768 + (wr * 128 + mh * 64) * 128;
#pragma unroll
    for (int mi = 0; mi < 4; ++mi) {
      v[mi][0] = *(const bf16x8*)(p + mi * 2048 + lo0);
      v[mi][1] = *(const bf16x8*)(p + mi * 2048 + lo1);
    }
  };
  auto LOAD_BV = [&](bf16x8 (&v)[2][2], int b, int nq) {
#pragma unroll
    for (int nj = 0; nj < 2; ++nj) {
      const int rb = wc * 64 + (nq * 2 + nj) * 16;
      const char* p = (const char*)lds + 65536 + b * 32768 + rb * 128;
      v[nj][0] = *(const bf16x8*)(p + lo0);
      v[nj][1] = *(const bf16x8*)(p + lo1);
    }
  };

// ks-outer: 16 independent MFMAs per ks -> no dependent back-to-back pairs
#define QUAD2(AV, BV0, BV1, MH)                                                \
  do {                                                                         \
    _Pragma("unroll") for (int ks = 0; ks < 2; ++ks) {                         \
      _Pragma("unroll") for (int mi = 0; mi < 4; ++mi) {                       \
        _Pragma("unroll") for (int nj = 0; nj < 2; ++nj) {                     \
          acc[(MH)*4 + mi][nj] = MFMA(AV[mi][ks], BV0[nj][ks], acc[(MH)*4 + mi][nj]); \
          acc[(MH)*4 + mi][2 + nj] = MFMA(AV[mi][ks], BV1[nj][ks], acc[(MH)*4 + mi][2 + nj]); \
        }                                                                      \
      }                                                                        \
    }                                                                          \
  } while (0)

  bf16x8 av[4][2], avh[4][2], bv0[2][2], bv1[2][2];

  // prologue: t0 all 4 half-tiles + B0(t1), A0(t1)
  STAGE(0, 0, 0, 0); STAGE(0, 0, 1, 0); STAGE(0, 1, 0, 0); STAGE(0, 1, 1, 0);
  STAGE(1, 1, 0, 1); STAGE(1, 0, 0, 1);
  asm volatile("s_waitcnt vmcnt(4)" ::: "memory");
  __builtin_amdgcn_sched_barrier(0);
  __builtin_amdgcn_s_barrier();

#pragma unroll 1
  for (int i = 0; i < NITER; ++i) {
    const int ta = 2 * i, tb = ta + 1;
    const bool st = (i + 1 < NITER);
    // M1: reads buf0 {A lo, B q0+q1}; stage A1(tb), B1(tb)
    LOAD_AV(av, 0, 0); LOAD_BV(bv0, 0, 0); LOAD_BV(bv1, 0, 1);
    STAGE(1, 0, 1, tb); STAGE(1, 1, 1, tb);
    PH_BAR();
    __builtin_amdgcn_s_setprio(1);
    QUAD2(av, bv0, bv1, 0);
    __builtin_amdgcn_s_setprio(0);
    PH_END();
    // M2: reads buf0 {A hi}; stage B0(ta+2), A0(ta+2); vmcnt -> tb landed
    LOAD_AV(avh, 0, 1);
    if (st) { STAGE(0, 1, 0, ta + 2); STAGE(0, 0, 0, ta + 2); }
    PH_BAR();
    __builtin_amdgcn_s_setprio(1);
    QUAD2(avh, bv0, bv1, 1);
    __builtin_amdgcn_s_setprio(0);
    if (st) asm volatile("s_waitcnt vmcnt(4)" ::: "memory");
    else    asm volatile("s_waitcnt vmcnt(0)" ::: "memory");
    PH_END();
    // M3: reads buf1 {A lo, B q0+q1}; stage A1(ta+2), B1(ta+2)
    LOAD_AV(av, 1, 0); LOAD_BV(bv0, 1, 0); LOAD_BV(bv1, 1, 1);
    if (st) { STAGE(0, 0, 1, ta + 2); STAGE(0, 1, 1, ta + 2); }
    PH_BAR();
    __builtin_amdgcn_s_setprio(1);
    QUAD2(av, bv0, bv1, 0);
    __builtin_amdgcn_s_setprio(0);
    PH_END();
    // M4: reads buf1 {A hi}; stage B0(tb+2), A0(tb+2); vmcnt -> ta+2 landed
    LOAD_AV(avh, 1, 1);
    if (st) { STAGE(1, 1, 0, tb + 2); STAGE(1, 0, 0, tb + 2); }
    PH_BAR();
    __builtin_amdgcn_s_setprio(1);
    QUAD2(avh, bv0, bv1, 1);
    __builtin_amdgcn_s_setprio(0);
    if (st) asm volatile("s_waitcnt vmcnt(4)" ::: "memory");
    PH_END();
  }

  // ---- epilogue: acc -> LDS (bf16, swizzled) -> coalesced dwordx4 stores ----
#pragma unroll
  for (int MI = 0; MI < 8; ++MI) {
    const int r0 = wr * 128 + MI * 16 + (lane >> 4) * 4;
#pragma unroll
    for (int NJ = 0; NJ < 4; ++NJ) {
      const int c = wc * 64 + NJ * 16 + (lane & 15);
#pragma unroll
      for (int j = 0; j < 4; ++j) {
        const int rr = r0 + j;
        *(u16*)((char*)lds + ((rr * 512 + c * 2) ^ ((rr & 7) << 4))) = f2bf(acc[MI][NJ][j]);
      }
    }
  }
  __syncthreads();
#pragma unroll
  for (int i = 0; i < 16; ++i) {
    const int rr = wid * 32 + i * 2 + (lane >> 5);
    const int unit = lane & 31;
    bf16x8 v = *(const bf16x8*)((const char*)lds + ((rr * 512 + unit * 16) ^ ((rr & 7) << 4)));
    *(bf16x8*)((u16*)OutV + (size_t)(m0 + rr) * N + bn0 + unit * 8) = v;
  }
}
#undef QUAD2

// ============ GEMM2: weight-folded, A-resident; FOLD hidden under MFMAs ============
__global__ __launch_bounds__(512, 2) void gemm_fold(
    const u16* __restrict__ A,    // h  [8192][256] bf16
    const u16* __restrict__ Bn,   // Rt [16][1024][256] bf16
    const float* __restrict__ W,  // Wr [8192][16] f32
    float* __restrict__ Out) {    // [8192][1024] f32
  __shared__ u16 ldsB[8][8192];   // 128 KB: 4 pair-buffers of 2 half-tiles
  __shared__ u16 Wlds[16][264];   // bf16 weights, [n][row]

  const int tid = threadIdx.x;
  const int lane = tid & 63;
  const int wid = tid >> 6;
  const int kh = wid >> 2;
  const int wrM = (wid >> 1) & 1;
  const int wcN = wid & 1;

  // L2-aware chunked XCD swizzle: chunk = 2 bx x 16 by (Rt slice 2MB <= L2)
  const int L = blockIdx.y * gridDim.x + blockIdx.x;
  const int ordered = (L & 7) * 64 + (L >> 3);
  const int cid = ordered >> 5, win = ordered & 31;
  const int bx = (cid & 3) * 2 + (win & 1);
  const int by = (cid >> 2) * 16 + (win >> 1);
  const int m0 = by * 128, d0 = bx * 128;

  const int arow = lane & 15;
  const int acol = (lane >> 4) * 16;
  const int sw = (arow & 7) << 4;
  const int lo0 = arow * 128 + (acol ^ sw);
  const int lo1 = arow * 128 + ((64 + acol) ^ sw);

  for (int i = tid; i < 128 * 16; i += 512) {
    const int row = i >> 4, n = i & 15;
    Wlds[n][row] = f2bf(W[(size_t)(m0 + row) * 16 + n]);
  }

  auto ASTAGE = [&](int kt) {
    const u16* G = A + (size_t)m0 * 256;
    u16* Lp = &ldsB[kt][0];
#pragma unroll
    for (int j = 0; j < 2; ++j) {
      const int q = j * 8192 + tid * 16;
      const int grow = q >> 7;
      const int gcol = ((q & 127) ^ (((q >> 7) & 7) << 4)) >> 1;
      gload16(G + (size_t)grow * 256 + kt * 64 + gcol, Lp + ((j * 8192 + wid * 1024) >> 1));
    }
  };
  ASTAGE(0); ASTAGE(1); ASTAGE(2); ASTAGE(3);
  __syncthreads();
  bf16x8 avk[4][4];
#pragma unroll
  for (int c2 = 0; c2 < 2; ++c2) {
#pragma unroll
    for (int mi = 0; mi < 4; ++mi) {
      const char* p = (const char*)&ldsB[kh * 2 + c2][0] + (wrM * 64 + mi * 16) * 128;
      avk[c2 * 2 + 0][mi] = *(const bf16x8*)(p + lo0);
      avk[c2 * 2 + 1][mi] = *(const bf16x8*)(p + lo1);
    }
  }
  __syncthreads();

  auto BSTAGE = [&](int ss) {
    const int n = ss >> 1, h = ss & 1, p = ss & 3;
    const u16* G = Bn + ((size_t)n * 1024 + d0) * 256;
#pragma unroll
    for (int t = 0; t < 2; ++t) {
      u16* Lp = &ldsB[2 * p + t][0];
      const int kt = h + 2 * t;
#pragma unroll
      for (int j = 0; j < 2; ++j) {
        const int q = j * 8192 + tid * 16;
        const int grow = q >> 7;
        const int gcol = ((q & 127) ^ (((q >> 7) & 7) << 4)) >> 1;
        gload16(G + (size_t)grow * 256 + kt * 64 + gcol, Lp + ((j * 8192 + wid * 1024) >> 1));
      }
    }
  };

  f32x4 acc_t[4][4], gA[4][4], gB[4][4];
#pragma unroll
  for (int mi = 0; mi < 4; ++mi)
#pragma unroll
    for (int nj = 0; nj < 4; ++nj) acc_t[mi][nj] = (f32x4){0.f, 0.f, 0.f, 0.f};
  const f32x4 vz = {0.f, 0.f, 0.f, 0.f};
  bf16x8 bv[4][2];
  u16x4 wpf[4];  // prefetched fold weights (register-only FOLD)

  auto BVLOAD = [&](int p) {
    const char* pB = (const char*)&ldsB[2 * p + kh][0];
#pragma unroll
    for (int nj = 0; nj < 4; ++nj) {
      const char* q = pB + (wcN * 64 + nj * 16) * 128;
      bv[nj][0] = *(const bf16x8*)(q + lo0);
      bv[nj][1] = *(const bf16x8*)(q + lo1);
    }
  };
  auto WPFL = [&](int n) {
#pragma unroll
    for (int mi = 0; mi < 4; ++mi)
      wpf[mi] = *(const u16x4*)&Wlds[n][wrM * 64 + mi * 16 + (lane >> 4) * 4];
  };

// group MFMA: FIRST -> ks==0 uses C=0 (no accumulator zeroing needed)
#define MFMA_GRP(G, H, FIRST)                                                  \
  do {                                                                         \
    _Pragma("unroll") for (int ks = 0; ks < 2; ++ks) {                         \
      _Pragma("unroll") for (int mi = 0; mi < 4; ++mi) {                       \
        _Pragma("unroll") for (int nj = 0; nj < 4; ++nj) {                     \
          G[mi][nj] = MFMA(avk[2 * (H) + ks][mi], bv[nj][ks],                  \
                           ((FIRST) && ks == 0) ? vz : G[mi][nj]);             \
        }                                                                      \
      }                                                                        \
    }                                                                          \
  } while (0)

// half-fold (2 mi rows), register-only: interleaves with MFMA cluster
#define FOLD_HALF(F, HB)                                                       \
  do {                                                                         \
    _Pragma("unroll") for (int mi = 2 * (HB); mi < 2 * (HB) + 2; ++mi) {       \
      const float w0 = bf2f(wpf[mi][0]), w1 = bf2f(wpf[mi][1]),                \
                  w2 = bf2f(wpf[mi][2]), w3 = bf2f(wpf[mi][3]);                \
      _Pragma("unroll") for (int nj = 0; nj < 4; ++nj) {                       \
        acc_t[mi][nj][0] += w0 * F[mi][nj][0];                                 \
        acc_t[mi][nj][1] += w1 * F[mi][nj][1];                                 \
        acc_t[mi][nj][2] += w2 * F[mi][nj][2];                                 \
        acc_t[mi][nj][3] += w3 * F[mi][nj][3];                                 \
      }                                                                        \
    }                                                                          \
  } while (0)

  BSTAGE(0); BSTAGE(1); BSTAGE(2);
  asm volatile("s_waitcnt vmcnt(8)" ::: "memory");
  __builtin_amdgcn_sched_barrier(0);
  __builtin_amdgcn_s_barrier();

#pragma unroll 1
  for (int np = 0; np < 8; ++np) {
    const int s0 = 4 * np;
    const bool last = (np == 7);
    // ss0: group 2np h0 -> gA (FIRST); fold gB(group 2np-1) half0
    BVLOAD(0); if (np) WPFL(2 * np - 1); BSTAGE(s0 + 3);
    PH_BAR();
    __builtin_amdgcn_s_setprio(1);
    if (np) FOLD_HALF(gB, 0);
    MFMA_GRP(gA, 0, true);
    __builtin_amdgcn_s_setprio(0);
    asm volatile("s_waitcnt vmcnt(8)" ::: "memory");
    PH_END();
    // ss1: group 2np h1 -> gA; fold gB half1
    BVLOAD(1); if (!last) BSTAGE(s0 + 4);
    PH_BAR();
    __builtin_amdgcn_s_setprio(1);
    if (np) FOLD_HALF(gB, 1);
    MFMA_GRP(gA, 1, false);
    __builtin_amdgcn_s_setprio(0);
    if (!last) asm volatile("s_waitcnt vmcnt(8)" ::: "memory");
    else       asm volatile("s_waitcnt vmcnt(4)" ::: "memory");
    PH_END();
    // ss2: group 2np+1 h0 -> gB (FIRST); fold gA(group 2np) half0
    BVLOAD(2); WPFL(2 * np); if (!last) BSTAGE(s0 + 5);
    PH_BAR();
    __builtin_amdgcn_s_setprio(1);
    FOLD_HALF(gA, 0);
    MFMA_GRP(gB, 0, true);
    __builtin_amdgcn_s_setprio(0);
    if (!last) asm volatile("s_waitcnt vmcnt(8)" ::: "memory");
    else       asm volatile("s_waitcnt vmcnt(0)" ::: "memory");
    PH_END();
    // ss3: group 2np+1 h1 -> gB; fold gA half1
    BVLOAD(3); if (!last) BSTAGE(s0 + 6);
    PH_BAR();
    __builtin_amdgcn_s_setprio(1);
    FOLD_HALF(gA, 1);
    MFMA_GRP(gB, 1, false);
    __builtin_amdgcn_s_setprio(0);
    if (!last) asm volatile("s_waitcnt vmcnt(8)" ::: "memory");
    PH_END();
  }
  // final fold: gB holds group 15
  WPFL(15);
  asm volatile("s_waitcnt lgkmcnt(0)" ::: "memory");
  __builtin_amdgcn_sched_barrier(0);
  FOLD_HALF(gB, 0);
  FOLD_HALF(gB, 1);
#undef MFMA_GRP
#undef FOLD_HALF

  // ---- epilogue: kh-reduce in LDS [128][128] f32 (swizzled), coalesced store ----
  __syncthreads();
  char* red = (char*)&ldsB[0][0];  // 64 KB used
  auto rb = [&](int r, int c) { return (r * 512 + c * 4) ^ ((r & 7) << 4); };
  if (kh == 1) {
#pragma unroll
    for (int mi = 0; mi < 4; ++mi)
#pragma unroll
      for (int j = 0; j < 4; ++j) {
        const int r = wrM * 64 + mi * 16 + (lane >> 4) * 4 + j;
#pragma unroll
        for (int nj = 0; nj < 4; ++nj)
          *(float*)(red + rb(r, wcN * 64 + nj * 16 + (lane & 15))) = acc_t[mi][nj][j];
      }
  }
  __syncthreads();
  if (kh == 0) {
#pragma unroll
    for (int mi = 0; mi < 4; ++mi)
#pragma unroll
      for (int j = 0; j < 4; ++j) {
        const int r = wrM * 64 + mi * 16 + (lane >> 4) * 4 + j;
#pragma unroll
        for (int nj = 0; nj < 4; ++nj) {
          float* p = (float*)(red + rb(r, wcN * 64 + nj * 16 + (lane & 15)));
          *p += acc_t[mi][nj][j];
        }
      }
  }
  __syncthreads();
#pragma unroll
  for (int i = 0; i < 8; ++i) {
    const int r = wid * 16 + i * 2 + (lane >> 5);
    const int unit = lane & 31;
    f32x4 v = *(const f32x4*)(red + ((r * 512 + unit * 16) ^ ((r & 7) << 4)));
    *(f32x4*)(Out + (size_t)(m0 + r) * 1024 + d0 + unit * 4) = v;
  }
}

extern "C" void kernel_launch(void* const* d_in, const int* in_sizes, int n_in,
                              void* d_out, int out_size, void* d_ws, size_t ws_size,
                              hipStream_t stream) {
  const float* x  = (const float*)d_in[0];   // [8192][1024]
  const float* F  = (const float*)d_in[1];   // [16][1024][256]
  const float* Rk = (const float*)d_in[2];   // [16][256][1024]
  const float* Wf = (const float*)d_in[3];   // [8192][16]
  const float* Wr = (const float*)d_in[4];   // [8192][16]
  float* out = (float*)d_out;                // [8192][1024]

  char* ws = (char*)d_ws;
  u16* X16 = (u16*)(ws);                 // 16 MB  x bf16 [8192][1024]
  u16* B1  = (u16*)(ws + (16u << 20));   //  8 MB  F^T  [(n,r)=4096][1024]
  u16* Rt  = (u16*)(ws + (24u << 20));   //  8 MB  Rk^T [16][1024][256]
  u16* T   = (u16*)(ws + (32u << 20));   // 64 MB  T bf16 [8192][4096]
  u16* h16 = (u16*)(ws);                 //  4 MB  h bf16 [8192][256] (reuses X16)

  cast_x_kernel<<<2048, 256, 0, stream>>>(x, X16, (M_TOK * 1024) / 4);
  tcast_kernel<<<dim3(8, 32, 16), 256, 0, stream>>>(F, B1, 1024, 256);
  tcast_kernel<<<dim3(32, 8, 16), 256, 0, stream>>>(Rk, Rt, 256, 1024);

  gemm256<16><<<dim3(16, 32, 1), 512, 0, stream>>>(X16, B1, T, 4096, 1024);
  combine_h<<<2048, 256, 0, stream>>>(T, Wf, h16);
  gemm_fold<<<dim3(8, 64, 1), 512, 0, stream>>>(h16, Rt, Wr, out);
}

// Round 9
// 169.783 us; speedup vs baseline: 2.1787x; 2.1787x over previous
//
#include <hip/hip_runtime.h>

typedef unsigned short u16;
typedef unsigned int u32;
typedef __attribute__((ext_vector_type(4))) float f32x4;
typedef __attribute__((ext_vector_type(8))) short bf16x8;
typedef __attribute__((ext_vector_type(4))) unsigned short u16x4;

#define MFMA(a, b, c) __builtin_amdgcn_mfma_f32_16x16x32_bf16((a), (b), (c), 0, 0, 0)

static constexpr int M_TOK = 8192;  // B*S

__device__ __forceinline__ u16 f2bf(float f) {
  u32 u = __float_as_uint(f);
  return (u16)((u + 0x7FFFu + ((u >> 16) & 1u)) >> 16);  // RNE
}
__device__ __forceinline__ float bf2f(u16 b) {
  u32 u = ((u32)b) << 16;
  return __uint_as_float(u);
}
__device__ __forceinline__ void gload16(const u16* g, u16* l) {
  __builtin_amdgcn_global_load_lds(
      (const __attribute__((address_space(1))) u32*)(const void*)g,
      (__attribute__((address_space(3))) u32*)(void*)l, 16, 0, 0);
}

#define PH_BAR()                                     \
  do {                                               \
    __builtin_amdgcn_sched_barrier(0);               \
    __builtin_amdgcn_s_barrier();                    \
    asm volatile("s_waitcnt lgkmcnt(0)" ::: "memory"); \
    __builtin_amdgcn_sched_barrier(0);               \
  } while (0)
#define PH_END()                       \
  do {                                 \
    __builtin_amdgcn_sched_barrier(0); \
    __builtin_amdgcn_s_barrier();      \
  } while (0)

// ---- elementwise fp32 -> bf16 cast ----
__global__ void cast_x_kernel(const float* __restrict__ in, u16* __restrict__ out, int total4) {
  for (int i = blockIdx.x * blockDim.x + threadIdx.x; i < total4; i += gridDim.x * blockDim.x) {
    float4 v = ((const float4*)in)[i];
    u16x4 o;
    o[0] = f2bf(v.x); o[1] = f2bf(v.y); o[2] = f2bf(v.z); o[3] = f2bf(v.w);
    ((u16x4*)out)[i] = o;
  }
}

// ---- transpose + cast: in [z][P][Q] fp32 -> out [z][Q][P] bf16 ----
__global__ void tcast_kernel(const float* __restrict__ in, u16* __restrict__ out, int P, int Q) {
  __shared__ float tile[32][33];
  const int z = blockIdx.z;
  const int q0 = blockIdx.x * 32, p0 = blockIdx.y * 32;
  const float* src = in + (size_t)z * P * Q;
  u16* dst = out + (size_t)z * P * Q;
  const int tx = threadIdx.x & 31, ty = threadIdx.x >> 5;
#pragma unroll
  for (int k = 0; k < 4; ++k)
    tile[ty + k * 8][tx] = src[(size_t)(p0 + ty + k * 8) * Q + q0 + tx];
  __syncthreads();
#pragma unroll
  for (int k = 0; k < 4; ++k)
    dst[(size_t)(q0 + ty + k * 8) * P + p0 + tx] = f2bf(tile[tx][ty + k * 8]);
}

// ---- h[m,r] = sum_n wf[m,n] * T[m, n*256+r] -> bf16 ----
__global__ void combine_h(const u16* __restrict__ T, const float* __restrict__ Wf,
                          u16* __restrict__ h) {
  const int m = blockIdx.x * 4 + (threadIdx.x >> 6);
  const int lane = threadIdx.x & 63;
  const u16* rowp = T + (size_t)m * 4096;
  float h0 = 0.f, h1 = 0.f, h2 = 0.f, h3 = 0.f;
#pragma unroll
  for (int n = 0; n < 16; ++n) {
    u16x4 v = *(const u16x4*)&rowp[n * 256 + lane * 4];
    const float wf = Wf[(size_t)m * 16 + n];
    h0 += wf * bf2f(v[0]); h1 += wf * bf2f(v[1]);
    h2 += wf * bf2f(v[2]); h3 += wf * bf2f(v[3]);
  }
  u16x4 o;
  o[0] = f2bf(h0); o[1] = f2bf(h1); o[2] = f2bf(h2); o[3] = f2bf(h3);
  *(u16x4*)&h[(size_t)m * 256 + lane * 4] = o;
}

// ================= GEMM1: 256x256, merged 4-phase, ks-outer MFMA =================
template <int NT>
__global__ __launch_bounds__(512, 2) void gemm256(
    const u16* __restrict__ A, const u16* __restrict__ Bm, void* __restrict__ OutV,
    const int N, const int K) {
  constexpr int NITER = NT / 2;
  __shared__ u16 lds[65536];  // A: [0,32K) u16, B: [32K,64K) u16 (128 KB)

  const int tid = threadIdx.x;
  const int lane = tid & 63;
  const int wid = tid >> 6;
  const int wr = wid >> 2, wc = wid & 3;

  // L2-aware chunked XCD swizzle (grid 16x32 = 512)
  const int L = blockIdx.y * gridDim.x + blockIdx.x;
  const int ordered = (L & 7) * 64 + (L >> 3);
  const int cid = ordered >> 5, win = ordered & 31;
  const int bx = (cid & 3) * 4 + (win & 3);
  const int by = (cid >> 2) * 8 + (win >> 2);
  const int m0 = by * 256, bn0 = bx * 256;

  const int arow = lane & 15;
  const int acol = (lane >> 4) * 16;
  const int sw = (arow & 7) << 4;
  const int lo0 = arow * 128 + (acol ^ sw);
  const int lo1 = arow * 128 + ((64 + acol) ^ sw);

  const u16* Abase = A + (size_t)m0 * K;
  const u16* Bbase = Bm + (size_t)bn0 * K;

  f32x4 acc[8][4];
#pragma unroll
  for (int i = 0; i < 8; ++i)
#pragma unroll
    for (int j = 0; j < 4; ++j) acc[i][j] = (f32x4){0.f, 0.f, 0.f, 0.f};

  auto STAGE = [&](int b, int isB, int hf, int kt) {
    const u16* G = isB ? Bbase : Abase;
    u16* Lp = &lds[isB * 32768 + (b * 2 + hf) * 8192];
#pragma unroll
    for (int j = 0; j < 2; ++j) {
      const int q = j * 8192 + tid * 16;
      const int grow = q >> 7;
      const int gcol = ((q & 127) ^ (((q >> 7) & 7) << 4)) >> 1;
      gload16(G + (size_t)(hf * 128 + grow) * K + kt * 64 + gcol,
              Lp + ((j * 8192 + wid * 1024) >> 1));
    }
  };
  auto LOAD_AV = [&](bf16x8 (&v)[4][2], int b, int mh) {
    const char* p = (const char*)lds + b * 32768 + (wr * 128 + mh * 64) * 128;
#pragma unroll
    for (int mi = 0; mi < 4; ++mi) {
      v[mi][0] = *(const bf16x8*)(p + mi * 2048 + lo0);
      v[mi][1] = *(const bf16x8*)(p + mi * 2048 + lo1);
    }
  };
  auto LOAD_BV = [&](bf16x8 (&v)[2][2], int b, int nq) {
#pragma unroll
    for (int nj = 0; nj < 2; ++nj) {
      const int rb = wc * 64 + (nq * 2 + nj) * 16;
      const char* p = (const char*)lds + 65536 + b * 32768 + rb * 128;
      v[nj][0] = *(const bf16x8*)(p + lo0);
      v[nj][1] = *(const bf16x8*)(p + lo1);
    }
  };

// ks-outer: 16 independent MFMAs per ks -> no dependent back-to-back pairs
#define QUAD2(AV, BV0, BV1, MH)                                                \
  do {                                                                         \
    _Pragma("unroll") for (int ks = 0; ks < 2; ++ks) {                         \
      _Pragma("unroll") for (int mi = 0; mi < 4; ++mi) {                       \
        _Pragma("unroll") for (int nj = 0; nj < 2; ++nj) {                     \
          acc[(MH)*4 + mi][nj] = MFMA(AV[mi][ks], BV0[nj][ks], acc[(MH)*4 + mi][nj]); \
          acc[(MH)*4 + mi][2 + nj] = MFMA(AV[mi][ks], BV1[nj][ks], acc[(MH)*4 + mi][2 + nj]); \
        }                                                                      \
      }                                                                        \
    }                                                                          \
  } while (0)

  bf16x8 av[4][2], avh[4][2], bv0[2][2], bv1[2][2];

  // prologue: t0 all 4 half-tiles + B0(t1), A0(t1)
  STAGE(0, 0, 0, 0); STAGE(0, 0, 1, 0); STAGE(0, 1, 0, 0); STAGE(0, 1, 1, 0);
  STAGE(1, 1, 0, 1); STAGE(1, 0, 0, 1);
  asm volatile("s_waitcnt vmcnt(4)" ::: "memory");
  __builtin_amdgcn_sched_barrier(0);
  __builtin_amdgcn_s_barrier();

#pragma unroll 1
  for (int i = 0; i < NITER; ++i) {
    const int ta = 2 * i, tb = ta + 1;
    const bool st = (i + 1 < NITER);
    // M1: reads buf0 {A lo, B q0+q1}; stage A1(tb), B1(tb)
    LOAD_AV(av, 0, 0); LOAD_BV(bv0, 0, 0); LOAD_BV(bv1, 0, 1);
    STAGE(1, 0, 1, tb); STAGE(1, 1, 1, tb);
    PH_BAR();
    __builtin_amdgcn_s_setprio(1);
    QUAD2(av, bv0, bv1, 0);
    __builtin_amdgcn_s_setprio(0);
    PH_END();
    // M2: reads buf0 {A hi}; stage B0(ta+2), A0(ta+2); vmcnt -> tb landed
    LOAD_AV(avh, 0, 1);
    if (st) { STAGE(0, 1, 0, ta + 2); STAGE(0, 0, 0, ta + 2); }
    PH_BAR();
    __builtin_amdgcn_s_setprio(1);
    QUAD2(avh, bv0, bv1, 1);
    __builtin_amdgcn_s_setprio(0);
    if (st) asm volatile("s_waitcnt vmcnt(4)" ::: "memory");
    else    asm volatile("s_waitcnt vmcnt(0)" ::: "memory");
    PH_END();
    // M3: reads buf1 {A lo, B q0+q1}; stage A1(ta+2), B1(ta+2)
    LOAD_AV(av, 1, 0); LOAD_BV(bv0, 1, 0); LOAD_BV(bv1, 1, 1);
    if (st) { STAGE(0, 0, 1, ta + 2); STAGE(0, 1, 1, ta + 2); }
    PH_BAR();
    __builtin_amdgcn_s_setprio(1);
    QUAD2(av, bv0, bv1, 0);
    __builtin_amdgcn_s_setprio(0);
    PH_END();
    // M4: reads buf1 {A hi}; stage B0(tb+2), A0(tb+2); vmcnt -> ta+2 landed
    LOAD_AV(avh, 1, 1);
    if (st) { STAGE(1, 1, 0, tb + 2); STAGE(1, 0, 0, tb + 2); }
    PH_BAR();
    __builtin_amdgcn_s_setprio(1);
    QUAD2(avh, bv0, bv1, 1);
    __builtin_amdgcn_s_setprio(0);
    if (st) asm volatile("s_waitcnt vmcnt(4)" ::: "memory");
    PH_END();
  }

  // ---- epilogue: acc -> LDS (bf16, swizzled) -> coalesced dwordx4 stores ----
#pragma unroll
  for (int MI = 0; MI < 8; ++MI) {
    const int r0 = wr * 128 + MI * 16 + (lane >> 4) * 4;
#pragma unroll
    for (int NJ = 0; NJ < 4; ++NJ) {
      const int c = wc * 64 + NJ * 16 + (lane & 15);
#pragma unroll
      for (int j = 0; j < 4; ++j) {
        const int rr = r0 + j;
        *(u16*)((char*)lds + ((rr * 512 + c * 2) ^ ((rr & 7) << 4))) = f2bf(acc[MI][NJ][j]);
      }
    }
  }
  __syncthreads();
#pragma unroll
  for (int i = 0; i < 16; ++i) {
    const int rr = wid * 32 + i * 2 + (lane >> 5);
    const int unit = lane & 31;
    bf16x8 v = *(const bf16x8*)((const char*)lds + ((rr * 512 + unit * 16) ^ ((rr & 7) << 4)));
    *(bf16x8*)((u16*)OutV + (size_t)(m0 + rr) * N + bn0 + unit * 8) = v;
  }
}
#undef QUAD2

// ============ GEMM2: weight-folded, A(h)-resident-in-registers (R6 known-good) ============
__global__ __launch_bounds__(512, 2) void gemm_fold(
    const u16* __restrict__ A,    // h  [8192][256] bf16
    const u16* __restrict__ Bn,   // Rt [16][1024][256] bf16
    const float* __restrict__ W,  // Wr [8192][16] f32
    float* __restrict__ Out) {    // [8192][1024] f32
  __shared__ u16 ldsB[8][8192];   // 128 KB: 4 pair-buffers of 2 half-tiles
  __shared__ u16 Wlds[16][264];   // bf16 weights, [n][row]

  const int tid = threadIdx.x;
  const int lane = tid & 63;
  const int wid = tid >> 6;
  const int kh = wid >> 2;
  const int wrM = (wid >> 1) & 1;
  const int wcN = wid & 1;

  // L2-aware chunked XCD swizzle: chunk = 2 bx x 16 by (Rt slice 2MB <= L2)
  const int L = blockIdx.y * gridDim.x + blockIdx.x;
  const int ordered = (L & 7) * 64 + (L >> 3);
  const int cid = ordered >> 5, win = ordered & 31;
  const int bx = (cid & 3) * 2 + (win & 1);
  const int by = (cid >> 2) * 16 + (win >> 1);
  const int m0 = by * 128, d0 = bx * 128;

  const int arow = lane & 15;
  const int acol = (lane >> 4) * 16;
  const int sw = (arow & 7) << 4;
  const int lo0 = arow * 128 + (acol ^ sw);
  const int lo1 = arow * 128 + ((64 + acol) ^ sw);

  for (int i = tid; i < 128 * 16; i += 512) {
    const int row = i >> 4, n = i & 15;
    Wlds[n][row] = f2bf(W[(size_t)(m0 + row) * 16 + n]);
  }

  auto ASTAGE = [&](int kt) {
    const u16* G = A + (size_t)m0 * 256;
    u16* Lp = &ldsB[kt][0];
#pragma unroll
    for (int j = 0; j < 2; ++j) {
      const int q = j * 8192 + tid * 16;
      const int grow = q >> 7;
      const int gcol = ((q & 127) ^ (((q >> 7) & 7) << 4)) >> 1;
      gload16(G + (size_t)grow * 256 + kt * 64 + gcol, Lp + ((j * 8192 + wid * 1024) >> 1));
    }
  };
  ASTAGE(0); ASTAGE(1); ASTAGE(2); ASTAGE(3);
  __syncthreads();
  bf16x8 avk[4][4];
#pragma unroll
  for (int c2 = 0; c2 < 2; ++c2) {
#pragma unroll
    for (int mi = 0; mi < 4; ++mi) {
      const char* p = (const char*)&ldsB[kh * 2 + c2][0] + (wrM * 64 + mi * 16) * 128;
      avk[c2 * 2 + 0][mi] = *(const bf16x8*)(p + lo0);
      avk[c2 * 2 + 1][mi] = *(const bf16x8*)(p + lo1);
    }
  }
  __syncthreads();

  auto BSTAGE = [&](int ss) {
    const int n = ss >> 1, h = ss & 1, p = ss & 3;
    const u16* G = Bn + ((size_t)n * 1024 + d0) * 256;
#pragma unroll
    for (int t = 0; t < 2; ++t) {
      u16* Lp = &ldsB[2 * p + t][0];
      const int kt = h + 2 * t;
#pragma unroll
      for (int j = 0; j < 2; ++j) {
        const int q = j * 8192 + tid * 16;
        const int grow = q >> 7;
        const int gcol = ((q & 127) ^ (((q >> 7) & 7) << 4)) >> 1;
        gload16(G + (size_t)grow * 256 + kt * 64 + gcol, Lp + ((j * 8192 + wid * 1024) >> 1));
      }
    }
  };

  f32x4 acc_t[4][4], acc_g[4][4];
#pragma unroll
  for (int mi = 0; mi < 4; ++mi)
#pragma unroll
    for (int nj = 0; nj < 4; ++nj) {
      acc_t[mi][nj] = (f32x4){0.f, 0.f, 0.f, 0.f};
      acc_g[mi][nj] = (f32x4){0.f, 0.f, 0.f, 0.f};
    }
  bf16x8 bv[4][2];

  BSTAGE(0); BSTAGE(1); BSTAGE(2);
  asm volatile("s_waitcnt vmcnt(8)" ::: "memory");
  __builtin_amdgcn_sched_barrier(0);
  __builtin_amdgcn_s_barrier();

  auto SSTEP = [&](int ss, int h, bool do_stage, int vmsel) {
    const int p = ss & 3;
    const char* pB = (const char*)&ldsB[2 * p + kh][0];
#pragma unroll
    for (int nj = 0; nj < 4; ++nj) {
      const char* q = pB + (wcN * 64 + nj * 16) * 128;
      bv[nj][0] = *(const bf16x8*)(q + lo0);
      bv[nj][1] = *(const bf16x8*)(q + lo1);
    }
    if (do_stage) BSTAGE(ss + 3);
    PH_BAR();
    __builtin_amdgcn_s_setprio(1);
#pragma unroll
    for (int ks = 0; ks < 2; ++ks)
#pragma unroll
      for (int mi = 0; mi < 4; ++mi)
#pragma unroll
        for (int nj = 0; nj < 4; ++nj)
          acc_g[mi][nj] = MFMA(avk[2 * h + ks][mi], bv[nj][ks], acc_g[mi][nj]);
    __builtin_amdgcn_s_setprio(0);
    if (vmsel == 8)      asm volatile("s_waitcnt vmcnt(8)" ::: "memory");
    else if (vmsel == 4) asm volatile("s_waitcnt vmcnt(4)" ::: "memory");
    else if (vmsel == 0) asm volatile("s_waitcnt vmcnt(0)" ::: "memory");
    PH_END();
  };
  auto FOLD = [&](int n) {
#pragma unroll
    for (int mi = 0; mi < 4; ++mi) {
      const int rbase = wrM * 64 + mi * 16 + (lane >> 4) * 4;
      u16x4 wq = *(const u16x4*)&Wlds[n][rbase];
      const float w0 = bf2f(wq[0]), w1 = bf2f(wq[1]), w2 = bf2f(wq[2]), w3 = bf2f(wq[3]);
#pragma unroll
      for (int nj = 0; nj < 4; ++nj) {
        acc_t[mi][nj][0] += w0 * acc_g[mi][nj][0];
        acc_t[mi][nj][1] += w1 * acc_g[mi][nj][1];
        acc_t[mi][nj][2] += w2 * acc_g[mi][nj][2];
        acc_t[mi][nj][3] += w3 * acc_g[mi][nj][3];
        acc_g[mi][nj] = (f32x4){0.f, 0.f, 0.f, 0.f};
      }
    }
  };

#pragma unroll 1
  for (int nn = 0; nn < 14; ++nn) {
    SSTEP(nn * 2 + 0, 0, true, 8);
    SSTEP(nn * 2 + 1, 1, true, 8);
    FOLD(nn);
  }
  SSTEP(28, 0, true, 8);
  SSTEP(29, 1, false, 4);
  FOLD(14);
  SSTEP(30, 0, false, 0);
  SSTEP(31, 1, false, -1);
  FOLD(15);

  // ---- epilogue: kh-reduce via LDS f32 regions, direct store (R6) ----
  __syncthreads();
  float* red = (float*)&ldsB[0][0];
  const int reg = (wrM * 2 + wcN) * 4096;
  if (kh == 1) {
#pragma unroll
    for (int mi = 0; mi < 4; ++mi)
#pragma unroll
      for (int j = 0; j < 4; ++j) {
        const int r = mi * 16 + (lane >> 4) * 4 + j;
#pragma unroll
        for (int nj = 0; nj < 4; ++nj)
          red[reg + r * 64 + nj * 16 + (lane & 15)] = acc_t[mi][nj][j];
      }
  }
  __syncthreads();
  if (kh == 0) {
#pragma unroll
    for (int mi = 0; mi < 4; ++mi) {
      const int rr = mi * 16 + (lane >> 4) * 4;
#pragma unroll
      for (int j = 0; j < 4; ++j) {
        float* orow = Out + (size_t)(m0 + wrM * 64 + rr + j) * 1024 + d0 + wcN * 64 + (lane & 15);
#pragma unroll
        for (int nj = 0; nj < 4; ++nj)
          orow[nj * 16] = acc_t[mi][nj][j] + red[reg + (rr + j) * 64 + nj * 16 + (lane & 15)];
      }
    }
  }
}

extern "C" void kernel_launch(void* const* d_in, const int* in_sizes, int n_in,
                              void* d_out, int out_size, void* d_ws, size_t ws_size,
                              hipStream_t stream) {
  const float* x  = (const float*)d_in[0];   // [8192][1024]
  const float* F  = (const float*)d_in[1];   // [16][1024][256]
  const float* Rk = (const float*)d_in[2];   // [16][256][1024]
  const float* Wf = (const float*)d_in[3];   // [8192][16]
  const float* Wr = (const float*)d_in[4];   // [8192][16]
  float* out = (float*)d_out;                // [8192][1024]

  char* ws = (char*)d_ws;
  u16* X16 = (u16*)(ws);                 // 16 MB  x bf16 [8192][1024]
  u16* B1  = (u16*)(ws + (16u << 20));   //  8 MB  F^T  [(n,r)=4096][1024]
  u16* Rt  = (u16*)(ws + (24u << 20));   //  8 MB  Rk^T [16][1024][256]
  u16* T   = (u16*)(ws + (32u << 20));   // 64 MB  T bf16 [8192][4096]
  u16* h16 = (u16*)(ws);                 //  4 MB  h bf16 [8192][256] (reuses X16)

  cast_x_kernel<<<2048, 256, 0, stream>>>(x, X16, (M_TOK * 1024) / 4);
  tcast_kernel<<<dim3(8, 32, 16), 256, 0, stream>>>(F, B1, 1024, 256);
  tcast_kernel<<<dim3(32, 8, 16), 256, 0, stream>>>(Rk, Rt, 256, 1024);

  gemm256<16><<<dim3(16, 32, 1), 512, 0, stream>>>(X16, B1, T, 4096, 1024);
  combine_h<<<2048, 256, 0, stream>>>(T, Wf, h16);
  gemm_fold<<<dim3(8, 64, 1), 512, 0, stream>>>(h16, Rt, Wr, out);
}

// Round 10
// 169.650 us; speedup vs baseline: 2.1804x; 1.0008x over previous
//
#include <hip/hip_runtime.h>

typedef unsigned short u16;
typedef unsigned int u32;
typedef __attribute__((ext_vector_type(4))) float f32x4;
typedef __attribute__((ext_vector_type(8))) short bf16x8;
typedef __attribute__((ext_vector_type(4))) unsigned short u16x4;

#define MFMA(a, b, c) __builtin_amdgcn_mfma_f32_16x16x32_bf16((a), (b), (c), 0, 0, 0)

static constexpr int M_TOK = 8192;  // B*S

__device__ __forceinline__ u16 f2bf(float f) {
  u32 u = __float_as_uint(f);
  return (u16)((u + 0x7FFFu + ((u >> 16) & 1u)) >> 16);  // RNE
}
__device__ __forceinline__ float bf2f(u16 b) {
  u32 u = ((u32)b) << 16;
  return __uint_as_float(u);
}
__device__ __forceinline__ void gload16(const u16* g, u16* l) {
  __builtin_amdgcn_global_load_lds(
      (const __attribute__((address_space(1))) u32*)(const void*)g,
      (__attribute__((address_space(3))) u32*)(void*)l, 16, 0, 0);
}

// m201-faithful: NO sched_barrier(0) in the hot loop — let the compiler
// interleave ds_read issue / MFMA / stage with its own counted lgkmcnt.
// (Rule 18 does not apply: ds_reads are compiler-visible C++ loads.)
#define PH_BAR()                                       \
  do {                                                 \
    __builtin_amdgcn_s_barrier();                      \
    asm volatile("s_waitcnt lgkmcnt(0)" ::: "memory"); \
  } while (0)
#define PH_END() __builtin_amdgcn_s_barrier()

// ---- elementwise fp32 -> bf16 cast ----
__global__ void cast_x_kernel(const float* __restrict__ in, u16* __restrict__ out, int total4) {
  for (int i = blockIdx.x * blockDim.x + threadIdx.x; i < total4; i += gridDim.x * blockDim.x) {
    float4 v = ((const float4*)in)[i];
    u16x4 o;
    o[0] = f2bf(v.x); o[1] = f2bf(v.y); o[2] = f2bf(v.z); o[3] = f2bf(v.w);
    ((u16x4*)out)[i] = o;
  }
}

// ---- transpose + cast: in [z][P][Q] fp32 -> out [z][Q][P] bf16 ----
__global__ void tcast_kernel(const float* __restrict__ in, u16* __restrict__ out, int P, int Q) {
  __shared__ float tile[32][33];
  const int z = blockIdx.z;
  const int q0 = blockIdx.x * 32, p0 = blockIdx.y * 32;
  const float* src = in + (size_t)z * P * Q;
  u16* dst = out + (size_t)z * P * Q;
  const int tx = threadIdx.x & 31, ty = threadIdx.x >> 5;
#pragma unroll
  for (int k = 0; k < 4; ++k)
    tile[ty + k * 8][tx] = src[(size_t)(p0 + ty + k * 8) * Q + q0 + tx];
  __syncthreads();
#pragma unroll
  for (int k = 0; k < 4; ++k)
    dst[(size_t)(q0 + ty + k * 8) * P + p0 + tx] = f2bf(tile[tx][ty + k * 8]);
}

// ---- h[m,r] = sum_n wf[m,n] * T[m, n*256+r] -> bf16 ----
__global__ void combine_h(const u16* __restrict__ T, const float* __restrict__ Wf,
                          u16* __restrict__ h) {
  const int m = blockIdx.x * 4 + (threadIdx.x >> 6);
  const int lane = threadIdx.x & 63;
  const u16* rowp = T + (size_t)m * 4096;
  float h0 = 0.f, h1 = 0.f, h2 = 0.f, h3 = 0.f;
#pragma unroll
  for (int n = 0; n < 16; ++n) {
    u16x4 v = *(const u16x4*)&rowp[n * 256 + lane * 4];
    const float wf = Wf[(size_t)m * 16 + n];
    h0 += wf * bf2f(v[0]); h1 += wf * bf2f(v[1]);
    h2 += wf * bf2f(v[2]); h3 += wf * bf2f(v[3]);
  }
  u16x4 o;
  o[0] = f2bf(h0); o[1] = f2bf(h1); o[2] = f2bf(h2); o[3] = f2bf(h3);
  *(u16x4*)&h[(size_t)m * 256 + lane * 4] = o;
}

// ================= GEMM1: 256x256, merged 4-phase, ks-outer MFMA =================
template <int NT>
__global__ __launch_bounds__(512, 2) void gemm256(
    const u16* __restrict__ A, const u16* __restrict__ Bm, void* __restrict__ OutV,
    const int N, const int K) {
  constexpr int NITER = NT / 2;
  __shared__ u16 lds[65536];  // A: [0,32K) u16, B: [32K,64K) u16 (128 KB)

  const int tid = threadIdx.x;
  const int lane = tid & 63;
  const int wid = tid >> 6;
  const int wr = wid >> 2, wc = wid & 3;

  // L2-aware chunked XCD swizzle (grid 16x32 = 512)
  const int L = blockIdx.y * gridDim.x + blockIdx.x;
  const int ordered = (L & 7) * 64 + (L >> 3);
  const int cid = ordered >> 5, win = ordered & 31;
  const int bx = (cid & 3) * 4 + (win & 3);
  const int by = (cid >> 2) * 8 + (win >> 2);
  const int m0 = by * 256, bn0 = bx * 256;

  const int arow = lane & 15;
  const int acol = (lane >> 4) * 16;
  const int sw = (arow & 7) << 4;
  const int lo0 = arow * 128 + (acol ^ sw);
  const int lo1 = arow * 128 + ((64 + acol) ^ sw);

  const u16* Abase = A + (size_t)m0 * K;
  const u16* Bbase = Bm + (size_t)bn0 * K;

  f32x4 acc[8][4];
#pragma unroll
  for (int i = 0; i < 8; ++i)
#pragma unroll
    for (int j = 0; j < 4; ++j) acc[i][j] = (f32x4){0.f, 0.f, 0.f, 0.f};

  auto STAGE = [&](int b, int isB, int hf, int kt) {
    const u16* G = isB ? Bbase : Abase;
    u16* Lp = &lds[isB * 32768 + (b * 2 + hf) * 8192];
#pragma unroll
    for (int j = 0; j < 2; ++j) {
      const int q = j * 8192 + tid * 16;
      const int grow = q >> 7;
      const int gcol = ((q & 127) ^ (((q >> 7) & 7) << 4)) >> 1;
      gload16(G + (size_t)(hf * 128 + grow) * K + kt * 64 + gcol,
              Lp + ((j * 8192 + wid * 1024) >> 1));
    }
  };
  auto LOAD_AV = [&](bf16x8 (&v)[4][2], int b, int mh) {
    const char* p = (const char*)lds + b * 32768 + (wr * 128 + mh * 64) * 128;
#pragma unroll
    for (int mi = 0; mi < 4; ++mi) {
      v[mi][0] = *(const bf16x8*)(p + mi * 2048 + lo0);
      v[mi][1] = *(const bf16x8*)(p + mi * 2048 + lo1);
    }
  };
  auto LOAD_BV = [&](bf16x8 (&v)[2][2], int b, int nq) {
#pragma unroll
    for (int nj = 0; nj < 2; ++nj) {
      const int rb = wc * 64 + (nq * 2 + nj) * 16;
      const char* p = (const char*)lds + 65536 + b * 32768 + rb * 128;
      v[nj][0] = *(const bf16x8*)(p + lo0);
      v[nj][1] = *(const bf16x8*)(p + lo1);
    }
  };

// ks-outer: 16 independent MFMAs per ks -> no dependent back-to-back pairs
#define QUAD2(AV, BV0, BV1, MH)                                                \
  do {                                                                         \
    _Pragma("unroll") for (int ks = 0; ks < 2; ++ks) {                         \
      _Pragma("unroll") for (int mi = 0; mi < 4; ++mi) {                       \
        _Pragma("unroll") for (int nj = 0; nj < 2; ++nj) {                     \
          acc[(MH)*4 + mi][nj] = MFMA(AV[mi][ks], BV0[nj][ks], acc[(MH)*4 + mi][nj]); \
          acc[(MH)*4 + mi][2 + nj] = MFMA(AV[mi][ks], BV1[nj][ks], acc[(MH)*4 + mi][2 + nj]); \
        }                                                                      \
      }                                                                        \
    }                                                                          \
  } while (0)

  bf16x8 av[4][2], avh[4][2], bv0[2][2], bv1[2][2];

  // prologue: t0 all 4 half-tiles + B0(t1), A0(t1)
  STAGE(0, 0, 0, 0); STAGE(0, 0, 1, 0); STAGE(0, 1, 0, 0); STAGE(0, 1, 1, 0);
  STAGE(1, 1, 0, 1); STAGE(1, 0, 0, 1);
  asm volatile("s_waitcnt vmcnt(4)" ::: "memory");
  __builtin_amdgcn_s_barrier();

#pragma unroll 1
  for (int i = 0; i < NITER; ++i) {
    const int ta = 2 * i, tb = ta + 1;
    const bool st = (i + 1 < NITER);
    // M1: reads buf0 {A lo, B q0+q1}; stage A1(tb), B1(tb)
    LOAD_AV(av, 0, 0); LOAD_BV(bv0, 0, 0); LOAD_BV(bv1, 0, 1);
    STAGE(1, 0, 1, tb); STAGE(1, 1, 1, tb);
    PH_BAR();
    __builtin_amdgcn_s_setprio(1);
    QUAD2(av, bv0, bv1, 0);
    __builtin_amdgcn_s_setprio(0);
    PH_END();
    // M2: reads buf0 {A hi}; stage B0(ta+2), A0(ta+2); vmcnt -> tb landed
    LOAD_AV(avh, 0, 1);
    if (st) { STAGE(0, 1, 0, ta + 2); STAGE(0, 0, 0, ta + 2); }
    PH_BAR();
    __builtin_amdgcn_s_setprio(1);
    QUAD2(avh, bv0, bv1, 1);
    __builtin_amdgcn_s_setprio(0);
    if (st) asm volatile("s_waitcnt vmcnt(4)" ::: "memory");
    else    asm volatile("s_waitcnt vmcnt(0)" ::: "memory");
    PH_END();
    // M3: reads buf1 {A lo, B q0+q1}; stage A1(ta+2), B1(ta+2)
    LOAD_AV(av, 1, 0); LOAD_BV(bv0, 1, 0); LOAD_BV(bv1, 1, 1);
    if (st) { STAGE(0, 0, 1, ta + 2); STAGE(0, 1, 1, ta + 2); }
    PH_BAR();
    __builtin_amdgcn_s_setprio(1);
    QUAD2(av, bv0, bv1, 0);
    __builtin_amdgcn_s_setprio(0);
    PH_END();
    // M4: reads buf1 {A hi}; stage B0(tb+2), A0(tb+2); vmcnt -> ta+2 landed
    LOAD_AV(avh, 1, 1);
    if (st) { STAGE(1, 1, 0, tb + 2); STAGE(1, 0, 0, tb + 2); }
    PH_BAR();
    __builtin_amdgcn_s_setprio(1);
    QUAD2(avh, bv0, bv1, 1);
    __builtin_amdgcn_s_setprio(0);
    if (st) asm volatile("s_waitcnt vmcnt(4)" ::: "memory");
    PH_END();
  }

  // ---- epilogue: acc -> LDS (bf16, swizzled) -> coalesced dwordx4 stores ----
#pragma unroll
  for (int MI = 0; MI < 8; ++MI) {
    const int r0 = wr * 128 + MI * 16 + (lane >> 4) * 4;
#pragma unroll
    for (int NJ = 0; NJ < 4; ++NJ) {
      const int c = wc * 64 + NJ * 16 + (lane & 15);
#pragma unroll
      for (int j = 0; j < 4; ++j) {
        const int rr = r0 + j;
        *(u16*)((char*)lds + ((rr * 512 + c * 2) ^ ((rr & 7) << 4))) = f2bf(acc[MI][NJ][j]);
      }
    }
  }
  __syncthreads();
#pragma unroll
  for (int i = 0; i < 16; ++i) {
    const int rr = wid * 32 + i * 2 + (lane >> 5);
    const int unit = lane & 31;
    bf16x8 v = *(const bf16x8*)((const char*)lds + ((rr * 512 + unit * 16) ^ ((rr & 7) << 4)));
    *(bf16x8*)((u16*)OutV + (size_t)(m0 + rr) * N + bn0 + unit * 8) = v;
  }
}
#undef QUAD2

// ============ GEMM2: weight-folded, A(h)-resident-in-registers ============
__global__ __launch_bounds__(512, 2) void gemm_fold(
    const u16* __restrict__ A,    // h  [8192][256] bf16
    const u16* __restrict__ Bn,   // Rt [16][1024][256] bf16
    const float* __restrict__ W,  // Wr [8192][16] f32
    float* __restrict__ Out) {    // [8192][1024] f32
  __shared__ u16 ldsB[8][8192];   // 128 KB: 4 pair-buffers of 2 half-tiles
  __shared__ u16 Wlds[16][264];   // bf16 weights, [n][row]

  const int tid = threadIdx.x;
  const int lane = tid & 63;
  const int wid = tid >> 6;
  const int kh = wid >> 2;
  const int wrM = (wid >> 1) & 1;
  const int wcN = wid & 1;

  // L2-aware chunked XCD swizzle: chunk = 2 bx x 16 by (Rt slice 2MB <= L2)
  const int L = blockIdx.y * gridDim.x + blockIdx.x;
  const int ordered = (L & 7) * 64 + (L >> 3);
  const int cid = ordered >> 5, win = ordered & 31;
  const int bx = (cid & 3) * 2 + (win & 1);
  const int by = (cid >> 2) * 16 + (win >> 1);
  const int m0 = by * 128, d0 = bx * 128;

  const int arow = lane & 15;
  const int acol = (lane >> 4) * 16;
  const int sw = (arow & 7) << 4;
  const int lo0 = arow * 128 + (acol ^ sw);
  const int lo1 = arow * 128 + ((64 + acol) ^ sw);

  for (int i = tid; i < 128 * 16; i += 512) {
    const int row = i >> 4, n = i & 15;
    Wlds[n][row] = f2bf(W[(size_t)(m0 + row) * 16 + n]);
  }

  auto ASTAGE = [&](int kt) {
    const u16* G = A + (size_t)m0 * 256;
    u16* Lp = &ldsB[kt][0];
#pragma unroll
    for (int j = 0; j < 2; ++j) {
      const int q = j * 8192 + tid * 16;
      const int grow = q >> 7;
      const int gcol = ((q & 127) ^ (((q >> 7) & 7) << 4)) >> 1;
      gload16(G + (size_t)grow * 256 + kt * 64 + gcol, Lp + ((j * 8192 + wid * 1024) >> 1));
    }
  };
  ASTAGE(0); ASTAGE(1); ASTAGE(2); ASTAGE(3);
  __syncthreads();
  bf16x8 avk[4][4];
#pragma unroll
  for (int c2 = 0; c2 < 2; ++c2) {
#pragma unroll
    for (int mi = 0; mi < 4; ++mi) {
      const char* p = (const char*)&ldsB[kh * 2 + c2][0] + (wrM * 64 + mi * 16) * 128;
      avk[c2 * 2 + 0][mi] = *(const bf16x8*)(p + lo0);
      avk[c2 * 2 + 1][mi] = *(const bf16x8*)(p + lo1);
    }
  }
  __syncthreads();

  auto BSTAGE = [&](int ss) {
    const int n = ss >> 1, h = ss & 1, p = ss & 3;
    const u16* G = Bn + ((size_t)n * 1024 + d0) * 256;
#pragma unroll
    for (int t = 0; t < 2; ++t) {
      u16* Lp = &ldsB[2 * p + t][0];
      const int kt = h + 2 * t;
#pragma unroll
      for (int j = 0; j < 2; ++j) {
        const int q = j * 8192 + tid * 16;
        const int grow = q >> 7;
        const int gcol = ((q & 127) ^ (((q >> 7) & 7) << 4)) >> 1;
        gload16(G + (size_t)grow * 256 + kt * 64 + gcol, Lp + ((j * 8192 + wid * 1024) >> 1));
      }
    }
  };

  f32x4 acc_t[4][4], acc_g[4][4];
#pragma unroll
  for (int mi = 0; mi < 4; ++mi)
#pragma unroll
    for (int nj = 0; nj < 4; ++nj) {
      acc_t[mi][nj] = (f32x4){0.f, 0.f, 0.f, 0.f};
      acc_g[mi][nj] = (f32x4){0.f, 0.f, 0.f, 0.f};
    }
  bf16x8 bv[4][2];

  BSTAGE(0); BSTAGE(1); BSTAGE(2);
  asm volatile("s_waitcnt vmcnt(8)" ::: "memory");
  __builtin_amdgcn_s_barrier();

  auto SSTEP = [&](int ss, int h, bool do_stage, int vmsel) {
    const int p = ss & 3;
    const char* pB = (const char*)&ldsB[2 * p + kh][0];
#pragma unroll
    for (int nj = 0; nj < 4; ++nj) {
      const char* q = pB + (wcN * 64 + nj * 16) * 128;
      bv[nj][0] = *(const bf16x8*)(q + lo0);
      bv[nj][1] = *(const bf16x8*)(q + lo1);
    }
    if (do_stage) BSTAGE(ss + 3);
    PH_BAR();
    __builtin_amdgcn_s_setprio(1);
#pragma unroll
    for (int ks = 0; ks < 2; ++ks)
#pragma unroll
      for (int mi = 0; mi < 4; ++mi)
#pragma unroll
        for (int nj = 0; nj < 4; ++nj)
          acc_g[mi][nj] = MFMA(avk[2 * h + ks][mi], bv[nj][ks], acc_g[mi][nj]);
    __builtin_amdgcn_s_setprio(0);
    if (vmsel == 8)      asm volatile("s_waitcnt vmcnt(8)" ::: "memory");
    else if (vmsel == 4) asm volatile("s_waitcnt vmcnt(4)" ::: "memory");
    else if (vmsel == 0) asm volatile("s_waitcnt vmcnt(0)" ::: "memory");
    PH_END();
  };
  auto FOLD = [&](int n) {
#pragma unroll
    for (int mi = 0; mi < 4; ++mi) {
      const int rbase = wrM * 64 + mi * 16 + (lane >> 4) * 4;
      u16x4 wq = *(const u16x4*)&Wlds[n][rbase];
      const float w0 = bf2f(wq[0]), w1 = bf2f(wq[1]), w2 = bf2f(wq[2]), w3 = bf2f(wq[3]);
#pragma unroll
      for (int nj = 0; nj < 4; ++nj) {
        acc_t[mi][nj][0] += w0 * acc_g[mi][nj][0];
        acc_t[mi][nj][1] += w1 * acc_g[mi][nj][1];
        acc_t[mi][nj][2] += w2 * acc_g[mi][nj][2];
        acc_t[mi][nj][3] += w3 * acc_g[mi][nj][3];
        acc_g[mi][nj] = (f32x4){0.f, 0.f, 0.f, 0.f};
      }
    }
  };

#pragma unroll 1
  for (int nn = 0; nn < 14; ++nn) {
    SSTEP(nn * 2 + 0, 0, true, 8);
    SSTEP(nn * 2 + 1, 1, true, 8);
    FOLD(nn);
  }
  SSTEP(28, 0, true, 8);
  SSTEP(29, 1, false, 4);
  FOLD(14);
  SSTEP(30, 0, false, 0);
  SSTEP(31, 1, false, -1);
  FOLD(15);

  // ---- epilogue: kh-reduce via LDS f32 regions, direct store ----
  __syncthreads();
  float* red = (float*)&ldsB[0][0];
  const int reg = (wrM * 2 + wcN) * 4096;
  if (kh == 1) {
#pragma unroll
    for (int mi = 0; mi < 4; ++mi)
#pragma unroll
      for (int j = 0; j < 4; ++j) {
        const int r = mi * 16 + (lane >> 4) * 4 + j;
#pragma unroll
        for (int nj = 0; nj < 4; ++nj)
          red[reg + r * 64 + nj * 16 + (lane & 15)] = acc_t[mi][nj][j];
      }
  }
  __syncthreads();
  if (kh == 0) {
#pragma unroll
    for (int mi = 0; mi < 4; ++mi) {
      const int rr = mi * 16 + (lane >> 4) * 4;
#pragma unroll
      for (int j = 0; j < 4; ++j) {
        float* orow = Out + (size_t)(m0 + wrM * 64 + rr + j) * 1024 + d0 + wcN * 64 + (lane & 15);
#pragma unroll
        for (int nj = 0; nj < 4; ++nj)
          orow[nj * 16] = acc_t[mi][nj][j] + red[reg + (rr + j) * 64 + nj * 16 + (lane & 15)];
      }
    }
  }
}

extern "C" void kernel_launch(void* const* d_in, const int* in_sizes, int n_in,
                              void* d_out, int out_size, void* d_ws, size_t ws_size,
                              hipStream_t stream) {
  const float* x  = (const float*)d_in[0];   // [8192][1024]
  const float* F  = (const float*)d_in[1];   // [16][1024][256]
  const float* Rk = (const float*)d_in[2];   // [16][256][1024]
  const float* Wf = (const float*)d_in[3];   // [8192][16]
  const float* Wr = (const float*)d_in[4];   // [8192][16]
  float* out = (float*)d_out;                // [8192][1024]

  char* ws = (char*)d_ws;
  u16* X16 = (u16*)(ws);                 // 16 MB  x bf16 [8192][1024]
  u16* B1  = (u16*)(ws + (16u << 20));   //  8 MB  F^T  [(n,r)=4096][1024]
  u16* Rt  = (u16*)(ws + (24u << 20));   //  8 MB  Rk^T [16][1024][256]
  u16* T   = (u16*)(ws + (32u << 20));   // 64 MB  T bf16 [8192][4096]
  u16* h16 = (u16*)(ws);                 //  4 MB  h bf16 [8192][256] (reuses X16)

  cast_x_kernel<<<2048, 256, 0, stream>>>(x, X16, (M_TOK * 1024) / 4);
  tcast_kernel<<<dim3(8, 32, 16), 256, 0, stream>>>(F, B1, 1024, 256);
  tcast_kernel<<<dim3(32, 8, 16), 256, 0, stream>>>(Rk, Rt, 256, 1024);

  gemm256<16><<<dim3(16, 32, 1), 512, 0, stream>>>(X16, B1, T, 4096, 1024);
  combine_h<<<2048, 256, 0, stream>>>(T, Wf, h16);
  gemm_fold<<<dim3(8, 64, 1), 512, 0, stream>>>(h16, Rt, Wr, out);
}

// Round 11
// 149.776 us; speedup vs baseline: 2.4697x; 1.1327x over previous
//
#include <hip/hip_runtime.h>

typedef unsigned short u16;
typedef unsigned int u32;
typedef __attribute__((ext_vector_type(4))) float f32x4;
typedef __attribute__((ext_vector_type(8))) short bf16x8;
typedef __attribute__((ext_vector_type(4))) unsigned short u16x4;

#define MFMA(a, b, c) __builtin_amdgcn_mfma_f32_16x16x32_bf16((a), (b), (c), 0, 0, 0)

static constexpr int M_TOK = 8192;  // B*S

__device__ __forceinline__ u16 f2bf(float f) {
  u32 u = __float_as_uint(f);
  return (u16)((u + 0x7FFFu + ((u >> 16) & 1u)) >> 16);  // RNE
}
__device__ __forceinline__ float bf2f(u16 b) {
  u32 u = ((u32)b) << 16;
  return __uint_as_float(u);
}
__device__ __forceinline__ void gload16(const u16* g, u16* l) {
  __builtin_amdgcn_global_load_lds(
      (const __attribute__((address_space(1))) u32*)(const void*)g,
      (__attribute__((address_space(3))) u32*)(void*)l, 16, 0, 0);
}

#define PH_BAR()                                       \
  do {                                                 \
    __builtin_amdgcn_s_barrier();                      \
    asm volatile("s_waitcnt lgkmcnt(0)" ::: "memory"); \
  } while (0)
#define PH_END() __builtin_amdgcn_s_barrier()

// ---- elementwise fp32 -> bf16 cast ----
__global__ void cast_x_kernel(const float* __restrict__ in, u16* __restrict__ out, int total4) {
  for (int i = blockIdx.x * blockDim.x + threadIdx.x; i < total4; i += gridDim.x * blockDim.x) {
    float4 v = ((const float4*)in)[i];
    u16x4 o;
    o[0] = f2bf(v.x); o[1] = f2bf(v.y); o[2] = f2bf(v.z); o[3] = f2bf(v.w);
    ((u16x4*)out)[i] = o;
  }
}

// ---- transpose + cast: in [z][P][Q] fp32 -> out [z][Q][P] bf16 ----
__global__ void tcast_kernel(const float* __restrict__ in, u16* __restrict__ out, int P, int Q) {
  __shared__ float tile[32][33];
  const int z = blockIdx.z;
  const int q0 = blockIdx.x * 32, p0 = blockIdx.y * 32;
  const float* src = in + (size_t)z * P * Q;
  u16* dst = out + (size_t)z * P * Q;
  const int tx = threadIdx.x & 31, ty = threadIdx.x >> 5;
#pragma unroll
  for (int k = 0; k < 4; ++k)
    tile[ty + k * 8][tx] = src[(size_t)(p0 + ty + k * 8) * Q + q0 + tx];
  __syncthreads();
#pragma unroll
  for (int k = 0; k < 4; ++k)
    dst[(size_t)(q0 + ty + k * 8) * P + p0 + tx] = f2bf(tile[tx][ty + k * 8]);
}

// ================= GEMM1+combine fused: h[m, bx*16+r] = sum_n wf[m,n]*(x@F_n) =================
// A: X16 [8192][1024]; Bm: B1 [(n*256+r)][1024]. Block = 256 m x (16 n x 16 r).
// B tile rows remapped: tile row tr -> global row (tr>>4)*256 + bx*16 + (tr&15).
// K-loop identical to the proven merged-4-phase gemm256. Epilogue: in-register
// float4 wf-weighted n-reduce (lane's 4 acc cols = 4 experts at fixed r),
// cross-wave LDS reduce, 4 MB bf16 h store. No T intermediate.
__global__ __launch_bounds__(512, 2) void gemm_h(
    const u16* __restrict__ A, const u16* __restrict__ Bm,
    const float* __restrict__ Wf, u16* __restrict__ Hout, const int K) {
  constexpr int NITER = 8;  // K=1024, 2 K-tiles per iter
  __shared__ u16 lds[65536];        // A: [0,32K) u16, B: [32K,64K) u16
  __shared__ float wf_lds[256 * 16];  // 16 KB

  const int tid = threadIdx.x;
  const int lane = tid & 63;
  const int wid = tid >> 6;
  const int wr = wid >> 2, wc = wid & 3;

  // L2-aware chunked XCD swizzle (grid 16x32 = 512)
  const int L = blockIdx.y * gridDim.x + blockIdx.x;
  const int ordered = (L & 7) * 64 + (L >> 3);
  const int cid = ordered >> 5, win = ordered & 31;
  const int bx = (cid & 3) * 4 + (win & 3);
  const int by = (cid >> 2) * 8 + (win >> 2);
  const int m0 = by * 256, bx16 = bx * 16;

  const int arow = lane & 15;
  const int acol = (lane >> 4) * 16;
  const int sw = (arow & 7) << 4;
  const int lo0 = arow * 128 + (acol ^ sw);
  const int lo1 = arow * 128 + ((64 + acol) ^ sw);

  const u16* Abase = A + (size_t)m0 * K;

  // stage wf rows m0..m0+255 (4096 floats, float4 x 2 per thread)
#pragma unroll
  for (int t = 0; t < 2; ++t) {
    const int i4 = t * 512 + tid;
    *(float4*)&wf_lds[i4 * 4] = *(const float4*)&Wf[(size_t)m0 * 16 + i4 * 4];
  }

  f32x4 acc[8][4];
#pragma unroll
  for (int i = 0; i < 8; ++i)
#pragma unroll
    for (int j = 0; j < 4; ++j) acc[i][j] = (f32x4){0.f, 0.f, 0.f, 0.f};

  auto STAGE = [&](int b, int isB, int hf, int kt) {
    u16* Lp = &lds[isB * 32768 + (b * 2 + hf) * 8192];
#pragma unroll
    for (int j = 0; j < 2; ++j) {
      const int q = j * 8192 + tid * 16;
      const int tr = hf * 128 + (q >> 7);  // tile row 0..255
      const int gcol = ((q & 127) ^ (((q >> 7) & 7) << 4)) >> 1;
      const u16* gp = isB
          ? Bm + (size_t)((tr >> 4) * 256 + bx16 + (tr & 15)) * K + kt * 64 + gcol
          : Abase + (size_t)tr * K + kt * 64 + gcol;
      gload16(gp, Lp + ((j * 8192 + wid * 1024) >> 1));
    }
  };
  auto LOAD_AV = [&](bf16x8 (&v)[4][2], int b, int mh) {
    const char* p = (const char*)lds + b * 32768 + (wr * 128 + mh * 64) * 128;
#pragma unroll
    for (int mi = 0; mi < 4; ++mi) {
      v[mi][0] = *(const bf16x8*)(p + mi * 2048 + lo0);
      v[mi][1] = *(const bf16x8*)(p + mi * 2048 + lo1);
    }
  };
  auto LOAD_BV = [&](bf16x8 (&v)[2][2], int b, int nq) {
#pragma unroll
    for (int nj = 0; nj < 2; ++nj) {
      const int rb = wc * 64 + (nq * 2 + nj) * 16;
      const char* p = (const char*)lds + 65536 + b * 32768 + rb * 128;
      v[nj][0] = *(const bf16x8*)(p + lo0);
      v[nj][1] = *(const bf16x8*)(p + lo1);
    }
  };

#define QUAD2(AV, BV0, BV1, MH)                                                \
  do {                                                                         \
    _Pragma("unroll") for (int ks = 0; ks < 2; ++ks) {                         \
      _Pragma("unroll") for (int mi = 0; mi < 4; ++mi) {                       \
        _Pragma("unroll") for (int nj = 0; nj < 2; ++nj) {                     \
          acc[(MH)*4 + mi][nj] = MFMA(AV[mi][ks], BV0[nj][ks], acc[(MH)*4 + mi][nj]); \
          acc[(MH)*4 + mi][2 + nj] = MFMA(AV[mi][ks], BV1[nj][ks], acc[(MH)*4 + mi][2 + nj]); \
        }                                                                      \
      }                                                                        \
    }                                                                          \
  } while (0)

  bf16x8 av[4][2], avh[4][2], bv0[2][2], bv1[2][2];

  // prologue: t0 all 4 half-tiles + B0(t1), A0(t1)
  STAGE(0, 0, 0, 0); STAGE(0, 0, 1, 0); STAGE(0, 1, 0, 0); STAGE(0, 1, 1, 0);
  STAGE(1, 1, 0, 1); STAGE(1, 0, 0, 1);
  asm volatile("s_waitcnt vmcnt(4)" ::: "memory");
  __builtin_amdgcn_s_barrier();

#pragma unroll 1
  for (int i = 0; i < NITER; ++i) {
    const int ta = 2 * i, tb = ta + 1;
    const bool st = (i + 1 < NITER);
    LOAD_AV(av, 0, 0); LOAD_BV(bv0, 0, 0); LOAD_BV(bv1, 0, 1);
    STAGE(1, 0, 1, tb); STAGE(1, 1, 1, tb);
    PH_BAR();
    __builtin_amdgcn_s_setprio(1);
    QUAD2(av, bv0, bv1, 0);
    __builtin_amdgcn_s_setprio(0);
    PH_END();
    LOAD_AV(avh, 0, 1);
    if (st) { STAGE(0, 1, 0, ta + 2); STAGE(0, 0, 0, ta + 2); }
    PH_BAR();
    __builtin_amdgcn_s_setprio(1);
    QUAD2(avh, bv0, bv1, 1);
    __builtin_amdgcn_s_setprio(0);
    if (st) asm volatile("s_waitcnt vmcnt(4)" ::: "memory");
    else    asm volatile("s_waitcnt vmcnt(0)" ::: "memory");
    PH_END();
    LOAD_AV(av, 1, 0); LOAD_BV(bv0, 1, 0); LOAD_BV(bv1, 1, 1);
    if (st) { STAGE(0, 0, 1, ta + 2); STAGE(0, 1, 1, ta + 2); }
    PH_BAR();
    __builtin_amdgcn_s_setprio(1);
    QUAD2(av, bv0, bv1, 0);
    __builtin_amdgcn_s_setprio(0);
    PH_END();
    LOAD_AV(avh, 1, 1);
    if (st) { STAGE(1, 1, 0, tb + 2); STAGE(1, 0, 0, tb + 2); }
    PH_BAR();
    __builtin_amdgcn_s_setprio(1);
    QUAD2(avh, bv0, bv1, 1);
    __builtin_amdgcn_s_setprio(0);
    if (st) asm volatile("s_waitcnt vmcnt(4)" ::: "memory");
    PH_END();
  }

  // ---- epilogue: lane's acc col (wc*64 + nj*16 + lane&15) = expert n=wc*4+nj,
  // r = lane&15. In-register wf-weighted n-reduce, then cross-wc LDS reduce.
  __syncthreads();
  float* pbuf = (float*)lds;  // [4 wc][256 m][16 r] f32 = 64 KB
#pragma unroll
  for (int MI = 0; MI < 8; ++MI) {
    const int mbase = wr * 128 + MI * 16 + (lane >> 4) * 4;
#pragma unroll
    for (int j = 0; j < 4; ++j) {
      const float4 wf4 = *(const float4*)&wf_lds[(mbase + j) * 16 + wc * 4];
      const float p = wf4.x * acc[MI][0][j] + wf4.y * acc[MI][1][j] +
                      wf4.z * acc[MI][2][j] + wf4.w * acc[MI][3][j];
      pbuf[wc * 4096 + (mbase + j) * 16 + (lane & 15)] = p;
    }
  }
  __syncthreads();
  {
    const int m = tid >> 1, r8 = (tid & 1) * 8;
    float s[8];
#pragma unroll
    for (int r = 0; r < 8; ++r) s[r] = 0.f;
#pragma unroll
    for (int w = 0; w < 4; ++w) {
      const float4 a = *(const float4*)&pbuf[w * 4096 + m * 16 + r8];
      const float4 b = *(const float4*)&pbuf[w * 4096 + m * 16 + r8 + 4];
      s[0] += a.x; s[1] += a.y; s[2] += a.z; s[3] += a.w;
      s[4] += b.x; s[5] += b.y; s[6] += b.z; s[7] += b.w;
    }
    bf16x8 o;
#pragma unroll
    for (int r = 0; r < 8; ++r) o[r] = (short)f2bf(s[r]);
    *(bf16x8*)&Hout[(size_t)(m0 + m) * 256 + bx16 + r8] = o;
  }
}
#undef QUAD2

// ============ GEMM2: weight-folded, A(h)-resident-in-registers (proven R6/R10) ============
__global__ __launch_bounds__(512, 2) void gemm_fold(
    const u16* __restrict__ A,    // h  [8192][256] bf16
    const u16* __restrict__ Bn,   // Rt [16][1024][256] bf16
    const float* __restrict__ W,  // Wr [8192][16] f32
    float* __restrict__ Out) {    // [8192][1024] f32
  __shared__ u16 ldsB[8][8192];   // 128 KB: 4 pair-buffers of 2 half-tiles
  __shared__ u16 Wlds[16][264];   // bf16 weights, [n][row]

  const int tid = threadIdx.x;
  const int lane = tid & 63;
  const int wid = tid >> 6;
  const int kh = wid >> 2;
  const int wrM = (wid >> 1) & 1;
  const int wcN = wid & 1;

  // L2-aware chunked XCD swizzle: chunk = 2 bx x 16 by (Rt slice 2MB <= L2)
  const int L = blockIdx.y * gridDim.x + blockIdx.x;
  const int ordered = (L & 7) * 64 + (L >> 3);
  const int cid = ordered >> 5, win = ordered & 31;
  const int bx = (cid & 3) * 2 + (win & 1);
  const int by = (cid >> 2) * 16 + (win >> 1);
  const int m0 = by * 128, d0 = bx * 128;

  const int arow = lane & 15;
  const int acol = (lane >> 4) * 16;
  const int sw = (arow & 7) << 4;
  const int lo0 = arow * 128 + (acol ^ sw);
  const int lo1 = arow * 128 + ((64 + acol) ^ sw);

  for (int i = tid; i < 128 * 16; i += 512) {
    const int row = i >> 4, n = i & 15;
    Wlds[n][row] = f2bf(W[(size_t)(m0 + row) * 16 + n]);
  }

  auto ASTAGE = [&](int kt) {
    const u16* G = A + (size_t)m0 * 256;
    u16* Lp = &ldsB[kt][0];
#pragma unroll
    for (int j = 0; j < 2; ++j) {
      const int q = j * 8192 + tid * 16;
      const int grow = q >> 7;
      const int gcol = ((q & 127) ^ (((q >> 7) & 7) << 4)) >> 1;
      gload16(G + (size_t)grow * 256 + kt * 64 + gcol, Lp + ((j * 8192 + wid * 1024) >> 1));
    }
  };
  ASTAGE(0); ASTAGE(1); ASTAGE(2); ASTAGE(3);
  __syncthreads();
  bf16x8 avk[4][4];
#pragma unroll
  for (int c2 = 0; c2 < 2; ++c2) {
#pragma unroll
    for (int mi = 0; mi < 4; ++mi) {
      const char* p = (const char*)&ldsB[kh * 2 + c2][0] + (wrM * 64 + mi * 16) * 128;
      avk[c2 * 2 + 0][mi] = *(const bf16x8*)(p + lo0);
      avk[c2 * 2 + 1][mi] = *(const bf16x8*)(p + lo1);
    }
  }
  __syncthreads();

  auto BSTAGE = [&](int ss) {
    const int n = ss >> 1, h = ss & 1, p = ss & 3;
    const u16* G = Bn + ((size_t)n * 1024 + d0) * 256;
#pragma unroll
    for (int t = 0; t < 2; ++t) {
      u16* Lp = &ldsB[2 * p + t][0];
      const int kt = h + 2 * t;
#pragma unroll
      for (int j = 0; j < 2; ++j) {
        const int q = j * 8192 + tid * 16;
        const int grow = q >> 7;
        const int gcol = ((q & 127) ^ (((q >> 7) & 7) << 4)) >> 1;
        gload16(G + (size_t)grow * 256 + kt * 64 + gcol, Lp + ((j * 8192 + wid * 1024) >> 1));
      }
    }
  };

  f32x4 acc_t[4][4], acc_g[4][4];
#pragma unroll
  for (int mi = 0; mi < 4; ++mi)
#pragma unroll
    for (int nj = 0; nj < 4; ++nj) {
      acc_t[mi][nj] = (f32x4){0.f, 0.f, 0.f, 0.f};
      acc_g[mi][nj] = (f32x4){0.f, 0.f, 0.f, 0.f};
    }
  bf16x8 bv[4][2];

  BSTAGE(0); BSTAGE(1); BSTAGE(2);
  asm volatile("s_waitcnt vmcnt(8)" ::: "memory");
  __builtin_amdgcn_s_barrier();

  auto SSTEP = [&](int ss, int h, bool do_stage, int vmsel) {
    const int p = ss & 3;
    const char* pB = (const char*)&ldsB[2 * p + kh][0];
#pragma unroll
    for (int nj = 0; nj < 4; ++nj) {
      const char* q = pB + (wcN * 64 + nj * 16) * 128;
      bv[nj][0] = *(const bf16x8*)(q + lo0);
      bv[nj][1] = *(const bf16x8*)(q + lo1);
    }
    if (do_stage) BSTAGE(ss + 3);
    PH_BAR();
    __builtin_amdgcn_s_setprio(1);
#pragma unroll
    for (int ks = 0; ks < 2; ++ks)
#pragma unroll
      for (int mi = 0; mi < 4; ++mi)
#pragma unroll
        for (int nj = 0; nj < 4; ++nj)
          acc_g[mi][nj] = MFMA(avk[2 * h + ks][mi], bv[nj][ks], acc_g[mi][nj]);
    __builtin_amdgcn_s_setprio(0);
    if (vmsel == 8)      asm volatile("s_waitcnt vmcnt(8)" ::: "memory");
    else if (vmsel == 4) asm volatile("s_waitcnt vmcnt(4)" ::: "memory");
    else if (vmsel == 0) asm volatile("s_waitcnt vmcnt(0)" ::: "memory");
    PH_END();
  };
  auto FOLD = [&](int n) {
#pragma unroll
    for (int mi = 0; mi < 4; ++mi) {
      const int rbase = wrM * 64 + mi * 16 + (lane >> 4) * 4;
      u16x4 wq = *(const u16x4*)&Wlds[n][rbase];
      const float w0 = bf2f(wq[0]), w1 = bf2f(wq[1]), w2 = bf2f(wq[2]), w3 = bf2f(wq[3]);
#pragma unroll
      for (int nj = 0; nj < 4; ++nj) {
        acc_t[mi][nj][0] += w0 * acc_g[mi][nj][0];
        acc_t[mi][nj][1] += w1 * acc_g[mi][nj][1];
        acc_t[mi][nj][2] += w2 * acc_g[mi][nj][2];
        acc_t[mi][nj][3] += w3 * acc_g[mi][nj][3];
        acc_g[mi][nj] = (f32x4){0.f, 0.f, 0.f, 0.f};
      }
    }
  };

#pragma unroll 1
  for (int nn = 0; nn < 14; ++nn) {
    SSTEP(nn * 2 + 0, 0, true, 8);
    SSTEP(nn * 2 + 1, 1, true, 8);
    FOLD(nn);
  }
  SSTEP(28, 0, true, 8);
  SSTEP(29, 1, false, 4);
  FOLD(14);
  SSTEP(30, 0, false, 0);
  SSTEP(31, 1, false, -1);
  FOLD(15);

  // ---- epilogue: kh-reduce via LDS f32 regions, direct store ----
  __syncthreads();
  float* red = (float*)&ldsB[0][0];
  const int reg = (wrM * 2 + wcN) * 4096;
  if (kh == 1) {
#pragma unroll
    for (int mi = 0; mi < 4; ++mi)
#pragma unroll
      for (int j = 0; j < 4; ++j) {
        const int r = mi * 16 + (lane >> 4) * 4 + j;
#pragma unroll
        for (int nj = 0; nj < 4; ++nj)
          red[reg + r * 64 + nj * 16 + (lane & 15)] = acc_t[mi][nj][j];
      }
  }
  __syncthreads();
  if (kh == 0) {
#pragma unroll
    for (int mi = 0; mi < 4; ++mi) {
      const int rr = mi * 16 + (lane >> 4) * 4;
#pragma unroll
      for (int j = 0; j < 4; ++j) {
        float* orow = Out + (size_t)(m0 + wrM * 64 + rr + j) * 1024 + d0 + wcN * 64 + (lane & 15);
#pragma unroll
        for (int nj = 0; nj < 4; ++nj)
          orow[nj * 16] = acc_t[mi][nj][j] + red[reg + (rr + j) * 64 + nj * 16 + (lane & 15)];
      }
    }
  }
}

extern "C" void kernel_launch(void* const* d_in, const int* in_sizes, int n_in,
                              void* d_out, int out_size, void* d_ws, size_t ws_size,
                              hipStream_t stream) {
  const float* x  = (const float*)d_in[0];   // [8192][1024]
  const float* F  = (const float*)d_in[1];   // [16][1024][256]
  const float* Rk = (const float*)d_in[2];   // [16][256][1024]
  const float* Wf = (const float*)d_in[3];   // [8192][16]
  const float* Wr = (const float*)d_in[4];   // [8192][16]
  float* out = (float*)d_out;                // [8192][1024]

  char* ws = (char*)d_ws;
  u16* X16 = (u16*)(ws);                 // 16 MB  x bf16 [8192][1024]
  u16* B1  = (u16*)(ws + (16u << 20));   //  8 MB  F^T  [(n,r)=4096][1024]
  u16* Rt  = (u16*)(ws + (24u << 20));   //  8 MB  Rk^T [16][1024][256]
  u16* h16 = (u16*)(ws + (32u << 20));   //  4 MB  h bf16 [8192][256] (own region: no alias with X16)

  cast_x_kernel<<<2048, 256, 0, stream>>>(x, X16, (M_TOK * 1024) / 4);
  tcast_kernel<<<dim3(8, 32, 16), 256, 0, stream>>>(F, B1, 1024, 256);
  tcast_kernel<<<dim3(32, 8, 16), 256, 0, stream>>>(Rk, Rt, 256, 1024);

  // fused stage 1: h = sum_n wf_n * (x @ F_n), no T intermediate
  gemm_h<<<dim3(16, 32, 1), 512, 0, stream>>>(X16, B1, Wf, h16, 1024);

  // stage 2: out = sum_n wr_n * (h @ Rt[n])
  gemm_fold<<<dim3(8, 64, 1), 512, 0, stream>>>(h16, Rt, Wr, out);
}